// Round 1
// baseline (20829.039 us; speedup 1.0000x reference)
//
#include <hip/hip_runtime.h>
#include <math.h>

// Problem constants
#define kB 256
#define kT 256
#define kD 512
#define kH 512
#define kO 256
#define kEPS 1e-5f

// Kernel config
#define NB 128        // persistent blocks (<=256 CUs -> all co-resident)
#define BT 256        // threads per block (one per batch row)
#define HCOL 4        // kH / NB columns owned per block
#define KTILE 64      // k-tile for x staging
#define XSS 257       // padded LDS row stride (+1 breaks bank conflicts)

// -------- grid barrier (device-scope, phase-indexed counters) --------
__device__ __forceinline__ void grid_barrier(int* bar, int phase) {
    __syncthreads();
    if (threadIdx.x == 0) {
        __hip_atomic_fetch_add(&bar[phase], 1, __ATOMIC_ACQ_REL, __HIP_MEMORY_SCOPE_AGENT);
        while (__hip_atomic_load(&bar[phase], __ATOMIC_ACQUIRE, __HIP_MEMORY_SCOPE_AGENT) < NB) {
            __builtin_amdgcn_s_sleep(1);
        }
    }
    __syncthreads();
}

// -------- block-wide BN stats: mean/rstd per owned column --------
// acc[HCOL] per thread (thread = batch row). red: HCOL*4*2 floats. sm/sr: HCOL.
__device__ __forceinline__ void block_bn_stats(const float acc[HCOL],
                                               float* sm, float* sr, float* red) {
    const int lane = threadIdx.x & 63;
    const int wid  = threadIdx.x >> 6;
#pragma unroll
    for (int c = 0; c < HCOL; ++c) {
        float s = acc[c];
        float q = acc[c] * acc[c];
#pragma unroll
        for (int off = 32; off > 0; off >>= 1) {
            s += __shfl_down(s, off, 64);
            q += __shfl_down(q, off, 64);
        }
        if (lane == 0) {
            red[(c * 4 + wid) * 2 + 0] = s;
            red[(c * 4 + wid) * 2 + 1] = q;
        }
    }
    __syncthreads();
    if (threadIdx.x < HCOL) {
        float s = 0.f, q = 0.f;
#pragma unroll
        for (int w = 0; w < 4; ++w) {
            s += red[(threadIdx.x * 4 + w) * 2 + 0];
            q += red[(threadIdx.x * 4 + w) * 2 + 1];
        }
        const float m   = s * (1.0f / kB);
        const float var = q * (1.0f / kB) - m * m;
        sm[threadIdx.x] = m;
        sr[threadIdx.x] = rsqrtf(var + kEPS);
    }
    __syncthreads();
}

// BN1 -> relu(+h*u) -> BN2; updates hprev in place (hprev becomes cell output)
__device__ __forceinline__ void cell_bn_tail(float acc[HCOL], float hprev[HCOL],
                                             const float pu[HCOL],
                                             const float pg1[HCOL], const float pbe1[HCOL],
                                             const float pg2[HCOL], const float pbe2[HCOL],
                                             float* sm, float* sr, float* red) {
    block_bn_stats(acc, sm, sr, red);
    float tmp[HCOL];
#pragma unroll
    for (int c = 0; c < HCOL; ++c) {
        const float zn = (acc[c] - sm[c]) * sr[c] * pg1[c] + pbe1[c];
        const float r  = zn + hprev[c] * pu[c];
        tmp[c] = r > 0.f ? r : 0.f;
    }
    block_bn_stats(tmp, sm, sr, red);
#pragma unroll
    for (int c = 0; c < HCOL; ++c) {
        hprev[c] = (tmp[c] - sm[c]) * sr[c] * pg2[c] + pbe2[c];
    }
}

__global__ __launch_bounds__(BT, 1) void indrnn_kernel(
    const float* __restrict__ x,
    const float* __restrict__ W0,  const float* __restrict__ b0,  const float* __restrict__ u0,
    const float* __restrict__ g10, const float* __restrict__ be10,
    const float* __restrict__ g20, const float* __restrict__ be20,
    const float* __restrict__ Wm,  const float* __restrict__ bm,  const float* __restrict__ um,
    const float* __restrict__ g1m, const float* __restrict__ be1m,
    const float* __restrict__ g2m, const float* __restrict__ be2m,
    const float* __restrict__ Wfc, const float* __restrict__ bfc,
    float* __restrict__ out,
    int* __restrict__ bar,
    float* __restrict__ h0T,   // 2 x [kH][kB]
    float* __restrict__ h1T,   // 2 x [kH][kB]
    float* __restrict__ h2n)   // [kB][kH]
{
    __shared__ float xs[KTILE * XSS];          // x tile, transposed [k][b] padded
    __shared__ float red[HCOL * 4 * 2];
    __shared__ float smean[HCOL], srstd[HCOL];
    __shared__ float hred[8];

    const int tid  = threadIdx.x;
    const int b    = tid;                       // batch row owned by this thread
    const int col0 = blockIdx.x * HCOL;         // first owned column

    // per-column params (wave-uniform -> SGPRs)
    float p_b0[HCOL], p_u0[HCOL], p_g10[HCOL], p_be10[HCOL], p_g20[HCOL], p_be20[HCOL];
    float p_bm[HCOL], p_um[HCOL], p_g1m[HCOL], p_be1m[HCOL], p_g2m[HCOL], p_be2m[HCOL];
#pragma unroll
    for (int c = 0; c < HCOL; ++c) {
        p_b0[c]  = b0[col0 + c];   p_u0[c]  = u0[col0 + c];
        p_g10[c] = g10[col0 + c];  p_be10[c] = be10[col0 + c];
        p_g20[c] = g20[col0 + c];  p_be20[c] = be20[col0 + c];
        p_bm[c]  = bm[col0 + c];   p_um[c]  = um[col0 + c];
        p_g1m[c] = g1m[col0 + c];  p_be1m[c] = be1m[col0 + c];
        p_g2m[c] = g2m[col0 + c];  p_be2m[c] = be2m[col0 + c];
    }

    float h0p[HCOL] = {0.f, 0.f, 0.f, 0.f};
    float h1p[HCOL] = {0.f, 0.f, 0.f, 0.f};
    float h2p[HCOL] = {0.f, 0.f, 0.f, 0.f};

    for (int t = 0; t < kT; ++t) {
        const int par = t & 1;
        float* h0w = h0T + (size_t)par * kH * kB;
        float* h1w = h1T + (size_t)par * kH * kB;

        // ================= cell 0: z = x_t @ W0^T =================
        float acc[HCOL];
#pragma unroll
        for (int c = 0; c < HCOL; ++c) acc[c] = p_b0[c];

        for (int kt = 0; kt < kD / KTILE; ++kt) {
            __syncthreads();   // previous tile consumers done
            // stage x[0:256][t][kt*64 .. +64] into xs[k][b] (transposed)
            const int l16 = tid & 15;
            const int rb  = tid >> 4;
#pragma unroll
            for (int pass = 0; pass < 16; ++pass) {
                const int row = rb + pass * 16;
                const float4 xv = *(const float4*)&x[((size_t)row * kT + t) * kD + kt * KTILE + l16 * 4];
                const int kk = l16 * 4;
                xs[(kk + 0) * XSS + row] = xv.x;
                xs[(kk + 1) * XSS + row] = xv.y;
                xs[(kk + 2) * XSS + row] = xv.z;
                xs[(kk + 3) * XSS + row] = xv.w;
            }
            __syncthreads();
            const float* w0p = W0 + (size_t)col0 * kD + kt * KTILE;
#pragma unroll 8
            for (int kl = 0; kl < KTILE; ++kl) {
                const float v = xs[kl * XSS + b];
#pragma unroll
                for (int c = 0; c < HCOL; ++c)
                    acc[c] = fmaf(v, w0p[(size_t)c * kD + kl], acc[c]);
            }
        }
        cell_bn_tail(acc, h0p, p_u0, p_g10, p_be10, p_g20, p_be20, smean, srstd, red);
#pragma unroll
        for (int c = 0; c < HCOL; ++c) h0w[(col0 + c) * kB + b] = h0p[c];
        grid_barrier(bar, 2 * t);

        // ================= cell 1: z = h0 @ Wm^T =================
#pragma unroll
        for (int c = 0; c < HCOL; ++c) acc[c] = p_bm[c];
        {
            const float* wmp = Wm + (size_t)col0 * kH;
#pragma unroll 8
            for (int k = 0; k < kH; ++k) {
                const float v = h0w[k * kB + b];
#pragma unroll
                for (int c = 0; c < HCOL; ++c)
                    acc[c] = fmaf(v, wmp[(size_t)c * kH + k], acc[c]);
            }
        }
        cell_bn_tail(acc, h1p, p_um, p_g1m, p_be1m, p_g2m, p_be2m, smean, srstd, red);
#pragma unroll
        for (int c = 0; c < HCOL; ++c) h1w[(col0 + c) * kB + b] = h1p[c];
        grid_barrier(bar, 2 * t + 1);

        // ================= cell 2: z = h1 @ Wm^T =================
#pragma unroll
        for (int c = 0; c < HCOL; ++c) acc[c] = p_bm[c];
        {
            const float* wmp = Wm + (size_t)col0 * kH;
#pragma unroll 8
            for (int k = 0; k < kH; ++k) {
                const float v = h1w[k * kB + b];
#pragma unroll
                for (int c = 0; c < HCOL; ++c)
                    acc[c] = fmaf(v, wmp[(size_t)c * kH + k], acc[c]);
            }
        }
        cell_bn_tail(acc, h2p, p_um, p_g1m, p_be1m, p_g2m, p_be2m, smean, srstd, red);
        if (t == kT - 1) {
#pragma unroll
            for (int c = 0; c < HCOL; ++c) h2n[(size_t)b * kH + col0 + c] = h2p[c];
        }
    }

    grid_barrier(bar, 2 * kT);   // h2n fully written

    // ================= head: logits + log_softmax, 2 rows/block =================
    for (int rr = 0; rr < 2; ++rr) {
        const int row = blockIdx.x * 2 + rr;
        __syncthreads();                       // guard xs / hred reuse
        xs[tid]       = h2n[(size_t)row * kH + tid];
        xs[tid + 256] = h2n[(size_t)row * kH + 256 + tid];
        __syncthreads();

        const int o = tid;
        float dot = bfc[o];
        const float* wf = Wfc + (size_t)o * kH;
#pragma unroll 8
        for (int h = 0; h < kH; ++h) dot = fmaf(xs[h], wf[h], dot);

        const int lane = tid & 63, wid = tid >> 6;
        float m = dot;
#pragma unroll
        for (int off = 32; off > 0; off >>= 1) m = fmaxf(m, __shfl_down(m, off, 64));
        if (lane == 0) hred[wid] = m;
        __syncthreads();
        const float M = fmaxf(fmaxf(hred[0], hred[1]), fmaxf(hred[2], hred[3]));
        float e = expf(dot - M);
        float s = e;
#pragma unroll
        for (int off = 32; off > 0; off >>= 1) s += __shfl_down(s, off, 64);
        if (lane == 0) hred[4 + wid] = s;
        __syncthreads();
        const float S = hred[4] + hred[5] + hred[6] + hred[7];
        out[(size_t)row * kO + o] = dot - M - logf(S);
    }
}

extern "C" void kernel_launch(void* const* d_in, const int* in_sizes, int n_in,
                              void* d_out, int out_size, void* d_ws, size_t ws_size,
                              hipStream_t stream) {
    const float* x    = (const float*)d_in[0];
    const float* W0   = (const float*)d_in[1];
    const float* b0   = (const float*)d_in[2];
    const float* u0   = (const float*)d_in[3];
    const float* g10  = (const float*)d_in[4];
    const float* be10 = (const float*)d_in[5];
    const float* g20  = (const float*)d_in[6];
    const float* be20 = (const float*)d_in[7];
    const float* Wm   = (const float*)d_in[8];
    const float* bm   = (const float*)d_in[9];
    const float* um   = (const float*)d_in[10];
    const float* g1m  = (const float*)d_in[11];
    const float* be1m = (const float*)d_in[12];
    const float* g2m  = (const float*)d_in[13];
    const float* be2m = (const float*)d_in[14];
    const float* Wfc  = (const float*)d_in[15];
    const float* bfc  = (const float*)d_in[16];
    float* out = (float*)d_out;

    char* ws = (char*)d_ws;
    int*   bar = (int*)ws;                                        // 4 KB barrier phases
    float* h0T = (float*)(ws + 4096);                             // 2 * 512 KB
    float* h1T = (float*)(ws + 4096 + 2 * (size_t)kH * kB * 4);   // 2 * 512 KB
    float* h2n = (float*)(ws + 4096 + 4 * (size_t)kH * kB * 4);   // 512 KB

    hipMemsetAsync(d_ws, 0, 4096, stream);   // zero barrier counters (ws is poisoned)

    hipLaunchKernelGGL(indrnn_kernel, dim3(NB), dim3(BT), 0, stream,
                       x, W0, b0, u0, g10, be10, g20, be20,
                       Wm, bm, um, g1m, be1m, g2m, be2m, Wfc, bfc,
                       out, bar, h0T, h1T, h2n);
}